// Round 13
// baseline (218.057 us; speedup 1.0000x reference)
//
#include <hip/hip_runtime.h>
#include <hip/hip_bf16.h>

#define GRID_W 64
#define NPTS   4096
#define BATCH  8
#define DD     32
#define DIN    80
#define HID    128
#define SH_STRIDE 136              // ushort stride (17*16B) -> conflict-free b128
#define SQ_STRIDE 36               // f32 stride for LDS state rows
#define NBLK   512                 // one grid-row per block
#define NSTEP  34                  // max half-steps for tf <= 4.0
#define SPIN_CAP 8192              // timeout => terminate w/ wrong data, never hang
// ws layout: [unused 128KB] | fragments | ebuf (tagged)
#define OFF_F1Q 131072
#define OFF_F2Q (OFF_F1Q + 24*64*16)
#define OFF_F1P (OFF_F2Q + 8*64*16)
#define OFF_F2P (OFF_F1P + 24*64*16)
#define OFF_EBUF 262144
// tagged ebuf: per (b,row,pt): 2 halves x 12 u64. u64 = [3 bf16 | tag].
// half: 4 quad-regions x 3 u64 (quad q: slots 8q..8q+2 | 8q+3..8q+5 | 8q+6,8q+7,dup)
// total = 512 rows * 64 pts * 24 u64 * 8B = 6 MB
#define EB_U64_TOTAL ((size_t)NBLK * 64 * 24)
#define WS_NEED ((size_t)OFF_EBUF + EB_U64_TOTAL * 8)

typedef __attribute__((ext_vector_type(8))) short short8;
typedef __attribute__((ext_vector_type(4))) float f32x4;
typedef unsigned long long u64;

__device__ __forceinline__ ushort f2bf(float v) {
    __hip_bfloat16 h = __float2bfloat16(v);
    return __builtin_bit_cast(ushort, h);
}
__device__ __forceinline__ uint packbf(float a, float b) {
    return (uint)f2bf(a) | ((uint)f2bf(b) << 16);
}
__device__ __forceinline__ short8 pack8(float4 a, float4 b) {
    union { uint u[4]; short8 s; } t;
    t.u[0] = packbf(a.x, a.y); t.u[1] = packbf(a.z, a.w);
    t.u[2] = packbf(b.x, b.y); t.u[3] = packbf(b.z, b.w);
    return t.s;
}
__device__ __forceinline__ float bf2f(ushort u) {
    union { uint i; float f; } t; t.i = ((uint)u) << 16; return t.f;
}

// Agent-scope u64 accessors (r10: measured identical to system scope on this
// protocol; LLC is the coherence point either way for cross-XCD exchange).
__device__ __forceinline__ u64 ld_sys64(const u64* p) {
    return __hip_atomic_load(p, __ATOMIC_RELAXED, __HIP_MEMORY_SCOPE_AGENT);
}
__device__ __forceinline__ void st_sys64(u64* p, u64 v) {
    __hip_atomic_store(p, v, __ATOMIC_RELAXED, __HIP_MEMORY_SCOPE_AGENT);
}

// ---- Tiny setup kernel: weight-fragment packing ONLY (2 blocks).
// Ebuf init is fused into sympl_coop (r13). Kernel-boundary writeback makes
// fragments visible to the coop launch.
__global__ void pack_weights(const float* __restrict__ W1q, const float* __restrict__ W2q,
                             const float* __restrict__ W1p, const float* __restrict__ W2p,
                             char* __restrict__ ws)
{
    const int s = blockIdx.x, tid = threadIdx.x;
    const float* W1 = s ? W1p : W1q;
    const float* W2 = s ? W2p : W2q;
    ushort* f1 = (ushort*)(ws + (s ? OFF_F1P : OFF_F1Q));
    ushort* f2 = (ushort*)(ws + (s ? OFF_F2P : OFF_F2Q));
    for (int idx = tid; idx < 24 * 512; idx += 256) {
        int f = idx >> 9, rem = idx & 511, lane = rem >> 3, j = rem & 7;
        int ks = f >> 3, nt = f & 7;
        int k = ks * 32 + (lane >> 4) * 8 + j, n = nt * 16 + (lane & 15);
        f1[idx] = f2bf(k < DIN ? W1[k * HID + n] : 0.0f);
    }
    for (int idx = tid; idx < 8 * 512; idx += 256) {
        int f = idx >> 9, rem = idx & 511, lane = rem >> 3, j = rem & 7;
        int ks = f >> 1, nt = f & 1;
        int k = ks * 32 + (lane >> 4) * 8 + j, n = nt * 16 + (lane & 15);
        f2[idx] = f2bf(W2[k * DD + n]);
    }
}

struct Acc2 { f32x4 a0, a1; };

// (fallback-only) full F-eval helper
__device__ __forceinline__ Acc2 eval_F(short8 af0, short8 af1, short8 af2,
    const short8* __restrict__ F1, const short8* __restrict__ w2,
    const float* __restrict__ B1, ushort* __restrict__ sH,
    int wv, int lane, int l16, int quad, int q8)
{
    f32x4 acc1[8];
    #pragma unroll
    for (int nt = 0; nt < 8; ++nt) acc1[nt] = (f32x4){0.f, 0.f, 0.f, 0.f};
    #pragma unroll
    for (int nt = 0; nt < 8; ++nt)
        acc1[nt] = __builtin_amdgcn_mfma_f32_16x16x32_bf16(af0, F1[nt * 64 + lane], acc1[nt], 0, 0, 0);
    #pragma unroll
    for (int nt = 0; nt < 8; ++nt)
        acc1[nt] = __builtin_amdgcn_mfma_f32_16x16x32_bf16(af1, F1[(8 + nt) * 64 + lane], acc1[nt], 0, 0, 0);
    #pragma unroll
    for (int nt = 0; nt < 8; ++nt)
        acc1[nt] = __builtin_amdgcn_mfma_f32_16x16x32_bf16(af2, F1[(16 + nt) * 64 + lane], acc1[nt], 0, 0, 0);
    #pragma unroll
    for (int nt = 0; nt < 8; ++nt) {
        const int col = nt * 16 + l16;
        const float bias = B1[col];
        #pragma unroll
        for (int rg = 0; rg < 4; ++rg) {
            const int rowm = wv * 16 + quad * 4 + rg;
            float s = acc1[nt][rg] + bias;
            float e = __expf(2.0f * s);
            float hh = 1.0f - __fdividef(2.0f, e + 1.0f);
            sH[rowm * SH_STRIDE + col] = f2bf(hh);
        }
    }
    Acc2 o;
    o.a0 = (f32x4){0.f, 0.f, 0.f, 0.f};
    o.a1 = (f32x4){0.f, 0.f, 0.f, 0.f};
    #pragma unroll
    for (int ks = 0; ks < 4; ++ks) {
        short8 af = *(const short8*)&sH[(wv * 16 + l16) * SH_STRIDE + ks * 32 + q8];
        o.a0 = __builtin_amdgcn_mfma_f32_16x16x32_bf16(af, w2[ks * 2 + 0], o.a0, 0, 0, 0);
        o.a1 = __builtin_amdgcn_mfma_f32_16x16x32_bf16(af, w2[ks * 2 + 1], o.a1, 0, 0, 0);
    }
    return o;
}

// Wave-autonomous rings with SELF-VALIDATING tagged exchange (r6/r10-proven).
// r13: ebuf tag-0 init FUSED into this kernel — each block rewrites its own
// row's 24 u64/pt (tag 0) from LDS after staging, then drains vmcnt once so
// later same-address publishes (tag 1+) cannot reorder ahead. Consumers'
// validated reads/sentinels spin until neighbor init lands (tag exact-match;
// SPIN_CAP bounds every wait). Cross-replay hygiene preserved: full rewrite
// each launch, stale tags can never equal this launch's expected sequence.
__global__ __launch_bounds__(256, 2) void sympl_coop(
    float* __restrict__ out, const float* __restrict__ x,
    const float* __restrict__ tfinal,
    char* __restrict__ ws,
    const float* __restrict__ b1q, const float* __restrict__ b2q,
    const float* __restrict__ b1p, const float* __restrict__ b2p)
{
    __shared__ __align__(16) float  sQ[64 * SQ_STRIDE];
    __shared__ __align__(16) float  sP[64 * SQ_STRIDE];
    __shared__ __align__(16) ushort sH[64 * SH_STRIDE];
    __shared__ __align__(16) float  sO[4 * 512];
    __shared__ uint ldsF[4];

    u64* eb = (u64*)(ws + OFF_EBUF);
    const int blk = blockIdx.x, tid = threadIdx.x;
    const int b = blk >> 6, r = blk & 63;
    const int wv = tid >> 6, lane = tid & 63;
    const int l16 = lane & 15, quad = lane >> 4, q8 = quad * 8;
    const int c = wv * 16 + l16;
    const int rm = (r + 63) & 63, rp = (r + 1) & 63;
    const int cm = (c + 63) & 63, cp = (c + 1) & 63;
    const int pt = tid >> 2, sg = (tid & 3) * 8;

    // neighbor-row chunk pointers (this lane's quad region of col c)
    const u64* prm = eb + ((size_t)(b * 64 + rm) * 64 + c) * 24 + quad * 3;
    const u64* prp = eb + ((size_t)(b * 64 + rp) * 64 + c) * 24 + quad * 3;
    // sentinel = last u64 the neighbor wave stores (pt wv*16+15, qR3,u2)
    const u64* s_rm = eb + ((size_t)(b * 64 + rm) * 64 + (wv * 16 + 15)) * 24 + 11;
    const u64* s_rp = eb + ((size_t)(b * 64 + rp) * 64 + (wv * 16 + 15)) * 24 + 11;
    u64* pub = eb + ((size_t)(b * 64 + r) * 64) * 24;

    // ---- init: own-row q/p from x -> LDS fp32; xi + W2 fragments -> regs ----
    {
        const float* src = x + (size_t)(b * NPTS + r * GRID_W + pt) * DIN;
        *(float4*)&sQ[pt * SQ_STRIDE + sg]     = *(const float4*)(src + sg);
        *(float4*)&sQ[pt * SQ_STRIDE + sg + 4] = *(const float4*)(src + sg + 4);
        *(float4*)&sP[pt * SQ_STRIDE + sg]     = *(const float4*)(src + DD + sg);
        *(float4*)&sP[pt * SQ_STRIDE + sg + 4] = *(const float4*)(src + DD + sg + 4);
    }
    if (tid < 4) ldsF[tid] = 0;
    short8 af2;
    if (quad < 2) {
        const float* px = x + (size_t)(b * NPTS + r * GRID_W + c) * DIN + 2 * DD + q8;
        af2 = pack8(*(const float4*)px, *(const float4*)(px + 4));
    } else {
        af2 = (short8)(short)0;
    }
    short8 w2q[8], w2p[8];
    {
        const short8* F2q = (const short8*)(ws + OFF_F2Q);
        const short8* F2p = (const short8*)(ws + OFF_F2P);
        #pragma unroll
        for (int i = 0; i < 8; ++i) { w2q[i] = F2q[i * 64 + lane]; w2p[i] = F2p[i * 64 + lane]; }
    }
    const float tf = tfinal[b];
    __syncthreads();                        // LDS state + ldsF visible (full drain)

    // ---- FUSED ebuf tag-0 init: 6 u64/thread from LDS, fire-and-forget,
    // then one vmcnt drain so later publishes to the same addresses cannot
    // reorder ahead of these init stores.
    {
        const float* rq = &sQ[pt * SQ_STRIDE];
        const float* rp_ = &sP[pt * SQ_STRIDE];
        const int j4 = tid & 3;
        #pragma unroll
        for (int k = 0; k < 6; ++k) {
            const int m = j4 * 6 + k;            // 0..23
            const int half = m / 12, sub = m % 12;
            const int qR = sub / 3, u = sub - qR * 3;
            const int sbase = qR * 8 + u * 3, cap = qR * 8 + 7;
            const int i1 = (sbase + 1 > cap) ? cap : sbase + 1;
            const int i2 = (sbase + 2 > cap) ? cap : sbase + 2;
            const float* hs = half ? rp_ : rq;
            u64 pk = (u64)f2bf(hs[sbase]) | ((u64)f2bf(hs[i1]) << 16)
                   | ((u64)f2bf(hs[i2]) << 32);   // tag ushort = 0
            st_sys64(pub + (size_t)pt * 24 + m, pk);
        }
        __asm__ volatile("s_waitcnt vmcnt(0)" ::: "memory");
    }

    const int wl = (wv + 3) & 3, wr = (wv + 1) & 3;

    float tq = 0.0f, tp = 0.0f;
    #pragma unroll 1
    for (int h = 0; h < NSTEP; ++h) {
        const int phase = h & 1;            // 0: q += dt*F(p); 1: p += dt*F(q)
        const float dtmax = phase ? 0.25f : ((h == 0) ? 0.125f : 0.25f);
        const float tcur  = phase ? tp : tq;
        if (!phase && tq >= tf) break;      // batch-uniform: all rings exit together
        const float dt = fminf(fmaxf(tf - tcur, 0.0f), dtmax);
        const int srcH = phase ^ 1;         // half read (q=0,p=1)
        const int dstH = phase;             // half written
        const float* srcL = phase ? sQ : sP;
        float*       dstL = phase ? sP : sQ;
        const short8* F1 = (const short8*)(ws + (phase ? OFF_F1P : OFF_F1Q));
        const uint hh = (uint)h;

        f32x4 acc1[8];
        if (dt > 0.0f) {                    // pre-wait: self + xi MFMAs
            const float* s0p = srcL + c * SQ_STRIDE + q8;
            float4 a0 = *(const float4*)s0p, a1 = *(const float4*)(s0p + 4);
            short8 af0 = pack8(a0, a1);
            #pragma unroll
            for (int nt = 0; nt < 8; ++nt) acc1[nt] = (f32x4){0.f, 0.f, 0.f, 0.f};
            #pragma unroll
            for (int nt = 0; nt < 8; ++nt)
                acc1[nt] = __builtin_amdgcn_mfma_f32_16x16x32_bf16(af0, F1[nt * 64 + lane], acc1[nt], 0, 0, 0);
            #pragma unroll
            for (int nt = 0; nt < 8; ++nt)
                acc1[nt] = __builtin_amdgcn_mfma_f32_16x16x32_bf16(af2, F1[(16 + nt) * 64 + lane], acc1[nt], 0, 0, 0);
        }

        // ---- wait: row sentinels (tagged data) + column LDS flags ----
        {
            int spins = 0;
            while (true) {
                bool ok = true;
                if (lane == 0)      ok = ((uint)(ld_sys64(s_rm + srcH * 12) >> 48) == hh);
                else if (lane == 1) ok = ((uint)(ld_sys64(s_rp + srcH * 12) >> 48) == hh);
                else if (lane == 2) ok = (__hip_atomic_load(&ldsF[wl], __ATOMIC_RELAXED, __HIP_MEMORY_SCOPE_WORKGROUP) >= hh);
                else if (lane == 3) ok = (__hip_atomic_load(&ldsF[wr], __ATOMIC_RELAXED, __HIP_MEMORY_SCOPE_WORKGROUP) >= hh);
                if (__all((int)ok)) break;
                if (++spins > SPIN_CAP) break;      // terminate, never hang
                __builtin_amdgcn_s_sleep(1);
            }
        }

        if (dt > 0.0f) {                    // block-uniform
            // validated neighbor loads: 6 self-validating u64 per lane
            const u64* pA = prm + srcH * 12;
            const u64* pB = prp + srcH * 12;
            u64 a0, a1, a2, c0, c1, c2;
            int spins = 0;
            while (true) {
                a0 = ld_sys64(pA);     a1 = ld_sys64(pA + 1); a2 = ld_sys64(pA + 2);
                c0 = ld_sys64(pB);     c1 = ld_sys64(pB + 1); c2 = ld_sys64(pB + 2);
                bool ok = ((uint)(a0 >> 48) == hh) & ((uint)(a1 >> 48) == hh)
                        & ((uint)(a2 >> 48) == hh) & ((uint)(c0 >> 48) == hh)
                        & ((uint)(c1 >> 48) == hh) & ((uint)(c2 >> 48) == hh);
                if (__all((int)ok)) break;
                if (++spins > SPIN_CAP) break;      // terminate, never hang
                __builtin_amdgcn_s_sleep(1);
            }

            // column neighbors (LDS) + row neighbors (loads) -> af1
            const float* smp = srcL + cm * SQ_STRIDE + q8;
            const float* spp = srcL + cp * SQ_STRIDE + q8;
            float4 lf0 = *(const float4*)smp, lf1 = *(const float4*)(smp + 4);
            float4 rt0 = *(const float4*)spp, rt1 = *(const float4*)(spp + 4);
            float4 m0, m1;
            m0.x = 0.25f * (bf2f((ushort)a0)         + bf2f((ushort)c0)         + lf0.x + rt0.x);
            m0.y = 0.25f * (bf2f((ushort)(a0 >> 16)) + bf2f((ushort)(c0 >> 16)) + lf0.y + rt0.y);
            m0.z = 0.25f * (bf2f((ushort)(a0 >> 32)) + bf2f((ushort)(c0 >> 32)) + lf0.z + rt0.z);
            m0.w = 0.25f * (bf2f((ushort)a1)         + bf2f((ushort)c1)         + lf0.w + rt0.w);
            m1.x = 0.25f * (bf2f((ushort)(a1 >> 16)) + bf2f((ushort)(c1 >> 16)) + lf1.x + rt1.x);
            m1.y = 0.25f * (bf2f((ushort)(a1 >> 32)) + bf2f((ushort)(c1 >> 32)) + lf1.y + rt1.y);
            m1.z = 0.25f * (bf2f((ushort)a2)         + bf2f((ushort)c2)         + lf1.z + rt1.z);
            m1.w = 0.25f * (bf2f((ushort)(a2 >> 16)) + bf2f((ushort)(c2 >> 16)) + lf1.w + rt1.w);
            short8 af1 = pack8(m0, m1);
            #pragma unroll
            for (int nt = 0; nt < 8; ++nt)
                acc1[nt] = __builtin_amdgcn_mfma_f32_16x16x32_bf16(af1, F1[(8 + nt) * 64 + lane], acc1[nt], 0, 0, 0);

            // tanh -> sH (wave-local rows)
            const float* B1 = phase ? b1p : b1q;
            #pragma unroll
            for (int nt = 0; nt < 8; ++nt) {
                const int col = nt * 16 + l16;
                const float bias = B1[col];
                #pragma unroll
                for (int rg = 0; rg < 4; ++rg) {
                    const int rowm = wv * 16 + quad * 4 + rg;
                    float s = acc1[nt][rg] + bias;
                    float e = __expf(2.0f * s);
                    float hhv = 1.0f - __fdividef(2.0f, e + 1.0f);
                    sH[rowm * SH_STRIDE + col] = f2bf(hhv);
                }
            }
            // GEMM2 (register-resident W2)
            const short8* w2 = phase ? w2p : w2q;
            f32x4 o0 = (f32x4){0.f, 0.f, 0.f, 0.f};
            f32x4 o1 = (f32x4){0.f, 0.f, 0.f, 0.f};
            #pragma unroll
            for (int ks = 0; ks < 4; ++ks) {
                short8 af = *(const short8*)&sH[(wv * 16 + l16) * SH_STRIDE + ks * 32 + q8];
                o0 = __builtin_amdgcn_mfma_f32_16x16x32_bf16(af, w2[ks * 2 + 0], o0, 0, 0, 0);
                o1 = __builtin_amdgcn_mfma_f32_16x16x32_bf16(af, w2[ks * 2 + 1], o1, 0, 0, 0);
            }
            // O -> wave-private sO
            float* sOw = sO + wv * 512;
            const float* B2 = phase ? b2p : b2q;
            #pragma unroll
            for (int nt = 0; nt < 2; ++nt) {
                const int col = nt * 16 + l16;
                const float b2v = B2[col];
                const f32x4 av = nt ? o1 : o0;
                #pragma unroll
                for (int rg = 0; rg < 4; ++rg)
                    sOw[(quad * 4 + rg) * DD + col] = av[rg] + b2v;
            }
            // LDS fp32 RMW (wave-private rows; LDS only — no global stores here)
            #pragma unroll
            for (int it = 0; it < 2; ++it) {
                const int slot = lane + it * 64;   // 128 float4 slots = 16 rows x 8
                const int lr = slot >> 3, seg = (slot & 7) * 4;
                const int pt_ = wv * 16 + lr;
                const float* po = &sOw[lr * DD + seg];
                float* pl = dstL + pt_ * SQ_STRIDE + seg;
                float4 o = *(const float4*)pl;
                o.x += dt * po[0]; o.y += dt * po[1];
                o.z += dt * po[2]; o.w += dt * po[3];
                *(float4*)pl = o;
            }
            // publish: 3 tagged u64 per lane (tag h+1), fire-and-forget
            const u64 tg = ((u64)(ushort)(hh + 1)) << 48;
            #pragma unroll
            for (int t = 0; t < 3; ++t) {
                const int g = t * 64 + lane;            // 0..191
                const int pt_ = g / 12, sub = g - pt_ * 12;
                const int qR = sub / 3, u = sub - qR * 3;
                const int sbase = qR * 8 + u * 3, cap = qR * 8 + 7;
                const int i1 = (sbase + 1 > cap) ? cap : sbase + 1;
                const int i2 = (sbase + 2 > cap) ? cap : sbase + 2;
                const float* pd = dstL + (wv * 16 + pt_) * SQ_STRIDE;
                u64 pk = (u64)f2bf(pd[sbase]) | ((u64)f2bf(pd[i1]) << 16)
                       | ((u64)f2bf(pd[i2]) << 32) | tg;
                st_sys64(pub + (size_t)(wv * 16 + pt_) * 24 + dstH * 12 + qR * 3 + u, pk);
            }
        }
        // column handshake: LDS writes drained, then per-wave flag
        __asm__ volatile("s_waitcnt lgkmcnt(0)" ::: "memory");
        if (lane == 0)
            __hip_atomic_store(&ldsF[wv], (uint)(h + 1), __ATOMIC_RELAXED, __HIP_MEMORY_SCOPE_WORKGROUP);
        if (phase) tp += dtmax; else tq += dtmax;
    }

    // ---- final state -> d_out: q, p from LDS; xi copied fp32 from x ----
    {
        float* dst = out + (size_t)(b * NPTS + r * GRID_W + pt) * DIN;
        const float* sx = x + (size_t)(b * NPTS + r * GRID_W + pt) * DIN;
        *(float4*)(dst + sg)          = *(const float4*)&sQ[pt * SQ_STRIDE + sg];
        *(float4*)(dst + sg + 4)      = *(const float4*)&sQ[pt * SQ_STRIDE + sg + 4];
        *(float4*)(dst + DD + sg)     = *(const float4*)&sP[pt * SQ_STRIDE + sg];
        *(float4*)(dst + DD + sg + 4) = *(const float4*)&sP[pt * SQ_STRIDE + sg + 4];
        const int xo = 2 * DD + (tid & 3) * 4;   // 16 xi floats / 4 threads
        *(float4*)(dst + xo) = *(const float4*)(sx + xo);
    }
}

// ---------------- fallback path (proven, global fp32 state) ----------------
__global__ __launch_bounds__(256, 2) void sympl_step(
    float* __restrict__ state, const float* __restrict__ tfinal,
    const char* __restrict__ ws,
    const float* __restrict__ B1, const float* __restrict__ B2,
    int phase, float tcur, float dtmax)
{
    __shared__ __align__(16) ushort sH[64 * SH_STRIDE];
    __shared__ __align__(16) float  sO[4 * 512];
    const int blk = blockIdx.x, tid = threadIdx.x;
    const int wv = tid >> 6, lane = tid & 63;
    const int l16 = lane & 15, quad = lane >> 4, q8 = quad * 8;
    const int b = blk >> 6, r = blk & 63;
    const int c = wv * 16 + l16;

    const float tf = tfinal[b];
    const float dt = fminf(fmaxf(tf - tcur, 0.0f), dtmax);
    if (dt <= 0.0f) return;

    const int srcoff = phase ? 0 : DD;
    const int dstoff = phase ? DD : 0;
    float* bb = state + (size_t)b * NPTS * DIN;
    const float* selfp = bb + (r * GRID_W + c) * DIN;
    const int rm = (r + 63) & 63, rp = (r + 1) & 63;
    const int cm = (c + 63) & 63, cp = (c + 1) & 63;
    short8 af0, af1, af2;
    {
        const float* ps = selfp + srcoff + q8;
        af0 = pack8(*(const float4*)ps, *(const float4*)(ps + 4));
    }
    {
        const float* p0 = bb + (rm * GRID_W + c) * DIN + srcoff + q8;
        const float* p1 = bb + (rp * GRID_W + c) * DIN + srcoff + q8;
        const float* p2 = bb + (r * GRID_W + cm) * DIN + srcoff + q8;
        const float* p3 = bb + (r * GRID_W + cp) * DIN + srcoff + q8;
        float4 a0 = *(const float4*)p0, a1 = *(const float4*)(p0 + 4);
        float4 b0 = *(const float4*)p1, b1v = *(const float4*)(p1 + 4);
        float4 c0 = *(const float4*)p2, c1 = *(const float4*)(p2 + 4);
        float4 d0 = *(const float4*)p3, d1 = *(const float4*)(p3 + 4);
        float4 m0, m1;
        m0.x = 0.25f * (a0.x + b0.x + c0.x + d0.x);
        m0.y = 0.25f * (a0.y + b0.y + c0.y + d0.y);
        m0.z = 0.25f * (a0.z + b0.z + c0.z + d0.z);
        m0.w = 0.25f * (a0.w + b0.w + c0.w + d0.w);
        m1.x = 0.25f * (a1.x + b1v.x + c1.x + d1.x);
        m1.y = 0.25f * (a1.y + b1v.y + c1.y + d1.y);
        m1.z = 0.25f * (a1.z + b1v.z + c1.z + d1.z);
        m1.w = 0.25f * (a1.w + b1v.w + c1.w + d1.w);
        af1 = pack8(m0, m1);
    }
    if (quad < 2) {
        const float* px = selfp + 2 * DD + q8;
        af2 = pack8(*(const float4*)px, *(const float4*)(px + 4));
    } else {
        af2 = (short8)(short)0;
    }
    const short8* F1 = (const short8*)(ws + (phase ? OFF_F1P : OFF_F1Q));
    const short8* F2 = (const short8*)(ws + (phase ? OFF_F2P : OFF_F2Q));
    short8 w2[8];
    #pragma unroll
    for (int i = 0; i < 8; ++i) w2[i] = F2[i * 64 + lane];
    Acc2 A = eval_F(af0, af1, af2, F1, w2, B1, sH, wv, lane, l16, quad, q8);
    float* sOw = sO + wv * 512;
    #pragma unroll
    for (int nt = 0; nt < 2; ++nt) {
        const int col = nt * 16 + l16;
        const float b2v = B2[col];
        const f32x4 av = nt ? A.a1 : A.a0;
        #pragma unroll
        for (int rg = 0; rg < 4; ++rg)
            sOw[(quad * 4 + rg) * DD + col] = av[rg] + b2v;
    }
    #pragma unroll
    for (int it = 0; it < 2; ++it) {
        const int slot = lane + it * 64;
        const int lr = slot >> 3, seg = (slot & 7) * 4;
        float* pd = bb + (r * GRID_W + wv * 16 + lr) * DIN + dstoff + seg;
        const float* po = &sOw[lr * DD + seg];
        float4 o = *(const float4*)pd;
        o.x += dt * po[0]; o.y += dt * po[1];
        o.z += dt * po[2]; o.w += dt * po[3];
        *(float4*)pd = o;
    }
}

extern "C" void kernel_launch(void* const* d_in, const int* in_sizes, int n_in,
                              void* d_out, int out_size, void* d_ws, size_t ws_size,
                              hipStream_t stream)
{
    const float* x   = (const float*)d_in[0];
    const float* tf  = (const float*)d_in[1];
    const float* W1q = (const float*)d_in[2];
    const float* b1q = (const float*)d_in[3];
    const float* W2q = (const float*)d_in[4];
    const float* b2q = (const float*)d_in[5];
    const float* W1p = (const float*)d_in[6];
    const float* b1p = (const float*)d_in[7];
    const float* W2p = (const float*)d_in[8];
    const float* b2p = (const float*)d_in[9];
    float* out = (float*)d_out;
    char* ws = (char*)d_ws;

    const int coop_ok = (ws_size >= WS_NEED) ? 1 : 0;

    // Tiny setup: weight-fragment packing only (2 blocks).
    pack_weights<<<dim3(2), dim3(256), 0, stream>>>(W1q, W2q, W1p, W2p, ws);

    if (coop_ok) {
        sympl_coop<<<dim3(NBLK), dim3(256), 0, stream>>>(
            out, x, tf, ws, b1q, b2q, b1p, b2p);
    } else {
        // Fallback: out <- x, then 34 regular launches (kernel-boundary coherence).
        hipMemcpyAsync(out, x, (size_t)BATCH * NPTS * DIN * sizeof(float),
                       hipMemcpyDeviceToDevice, stream);
        float tq = 0.0f, tp = 0.0f;
        for (int h = 0; h < NSTEP; ++h) {
            const int phase = h & 1;
            const float dtmax = phase ? 0.25f : ((h == 0) ? 0.125f : 0.25f);
            const float tcur  = phase ? tp : tq;
            sympl_step<<<dim3(NBLK), dim3(256), 0, stream>>>(
                out, tf, ws, phase ? b1p : b1q, phase ? b2p : b2q,
                phase, tcur, dtmax);
            if (phase) tp += dtmax; else tq += dtmax;
        }
    }
}

// Round 14
// 213.981 us; speedup vs baseline: 1.0190x; 1.0190x over previous
//
#include <hip/hip_runtime.h>
#include <hip/hip_bf16.h>

#define GRID_W 64
#define NPTS   4096
#define BATCH  8
#define DD     32
#define DIN    80
#define HID    128
#define SH_STRIDE 136              // ushort stride (17*16B) -> conflict-free b128
#define SQ_STRIDE 36               // f32 stride for LDS state rows
#define NBLK   512                 // one grid-row per block
#define NSTEP  34                  // max half-steps for tf <= 4.0
#define SPIN_CAP 8192              // timeout => terminate w/ wrong data, never hang
// ws layout: [unused 128KB] | fragments | ebuf (tagged)
#define OFF_F1Q 131072
#define OFF_F2Q (OFF_F1Q + 24*64*16)
#define OFF_F1P (OFF_F2Q + 8*64*16)
#define OFF_F2P (OFF_F1P + 24*64*16)
#define OFF_EBUF 262144
// tagged ebuf: per (b,row,pt): 2 halves x 12 u64. u64 = [3 bf16 | tag].
// half: 4 quad-regions x 3 u64 (quad q: slots 8q..8q+2 | 8q+3..8q+5 | 8q+6,8q+7,dup)
// total = 512 rows * 64 pts * 24 u64 * 8B = 6 MB
#define EB_U64_TOTAL ((size_t)NBLK * 64 * 24)
#define WS_NEED ((size_t)OFF_EBUF + EB_U64_TOTAL * 8)

typedef __attribute__((ext_vector_type(8))) short short8;
typedef __attribute__((ext_vector_type(4))) float f32x4;
typedef unsigned long long u64;

__device__ __forceinline__ ushort f2bf(float v) {
    __hip_bfloat16 h = __float2bfloat16(v);
    return __builtin_bit_cast(ushort, h);
}
__device__ __forceinline__ uint packbf(float a, float b) {
    return (uint)f2bf(a) | ((uint)f2bf(b) << 16);
}
__device__ __forceinline__ short8 pack8(float4 a, float4 b) {
    union { uint u[4]; short8 s; } t;
    t.u[0] = packbf(a.x, a.y); t.u[1] = packbf(a.z, a.w);
    t.u[2] = packbf(b.x, b.y); t.u[3] = packbf(b.z, b.w);
    return t.s;
}
__device__ __forceinline__ float bf2f(ushort u) {
    union { uint i; float f; } t; t.i = ((uint)u) << 16; return t.f;
}

// Agent-scope u64 accessors (r10: measured identical to system scope on this
// protocol; LLC is the coherence point either way for cross-XCD exchange).
__device__ __forceinline__ u64 ld_sys64(const u64* p) {
    return __hip_atomic_load(p, __ATOMIC_RELAXED, __HIP_MEMORY_SCOPE_AGENT);
}
__device__ __forceinline__ void st_sys64(u64* p, u64 v) {
    __hip_atomic_store(p, v, __ATOMIC_RELAXED, __HIP_MEMORY_SCOPE_AGENT);
}

// ---- ONE setup kernel (r12-proven best: no x->out copy; LDS-staged ebuf).
// Blocks 0..511: build tagged ebuf row (tag=0) from x via coalesced float4
// reads + LDS scalars. Blocks 512/513: pack W1/W2 MFMA fragments.
// Plain stores; kernel-boundary writeback makes all lines LLC-visible.
__global__ void setup_all(const float* __restrict__ x,
                          char* __restrict__ ws,
                          const float* __restrict__ W1q, const float* __restrict__ W2q,
                          const float* __restrict__ W1p, const float* __restrict__ W2p,
                          int do_ebuf)
{
    __shared__ float st[64 * 64];   // [pt][0..31 q | 32..63 p]
    const int blk = blockIdx.x, tid = threadIdx.x;
    if (blk >= NBLK) {
        const int s = blk - NBLK;
        const float* W1 = s ? W1p : W1q;
        const float* W2 = s ? W2p : W2q;
        ushort* f1 = (ushort*)(ws + (s ? OFF_F1P : OFF_F1Q));
        ushort* f2 = (ushort*)(ws + (s ? OFF_F2P : OFF_F2Q));
        for (int idx = tid; idx < 24 * 512; idx += 256) {
            int f = idx >> 9, rem = idx & 511, lane = rem >> 3, j = rem & 7;
            int ks = f >> 3, nt = f & 7;
            int k = ks * 32 + (lane >> 4) * 8 + j, n = nt * 16 + (lane & 15);
            f1[idx] = f2bf(k < DIN ? W1[k * HID + n] : 0.0f);
        }
        for (int idx = tid; idx < 8 * 512; idx += 256) {
            int f = idx >> 9, rem = idx & 511, lane = rem >> 3, j = rem & 7;
            int ks = f >> 1, nt = f & 1;
            int k = ks * 32 + (lane >> 4) * 8 + j, n = nt * 16 + (lane & 15);
            f2[idx] = f2bf(W2[k * DD + n]);
        }
        return;
    }
    if (!do_ebuf) return;
    const int b = blk >> 6, r = blk & 63;
    const int pt = tid >> 2, j4 = tid & 3, sg = j4 * 8;
    // coalesced q/p -> LDS
    {
        const float* src = x + (size_t)(b * NPTS + r * GRID_W + pt) * DIN;
        *(float4*)&st[pt * 64 + sg]          = *(const float4*)(src + sg);
        *(float4*)&st[pt * 64 + sg + 4]      = *(const float4*)(src + sg + 4);
        *(float4*)&st[pt * 64 + 32 + sg]     = *(const float4*)(src + DD + sg);
        *(float4*)&st[pt * 64 + 32 + sg + 4] = *(const float4*)(src + DD + sg + 4);
    }
    __syncthreads();
    // tagged ebuf: 6 u64 per thread, contiguous stores per pt, tag = 0
    u64* drow = (u64*)(ws + OFF_EBUF) + ((size_t)((b * 64 + r) * 64) + pt) * 24;
    const float* hs0 = &st[pt * 64];
    #pragma unroll
    for (int k = 0; k < 6; ++k) {
        const int m = j4 * 6 + k;            // 0..23 (== drow index)
        const int half = m / 12, sub = m % 12;
        const int qR = sub / 3, u = sub - qR * 3;
        const int sbase = qR * 8 + u * 3, cap = qR * 8 + 7;
        const int i1 = (sbase + 1 > cap) ? cap : sbase + 1;
        const int i2 = (sbase + 2 > cap) ? cap : sbase + 2;
        const float* hs = hs0 + (half ? 32 : 0);
        u64 pk = (u64)f2bf(hs[sbase]) | ((u64)f2bf(hs[i1]) << 16)
               | ((u64)f2bf(hs[i2]) << 32);   // tag ushort = 0
        drow[m] = pk;
    }
}

struct Acc2 { f32x4 a0, a1; };

// (fallback-only) full F-eval helper
__device__ __forceinline__ Acc2 eval_F(short8 af0, short8 af1, short8 af2,
    const short8* __restrict__ F1, const short8* __restrict__ w2,
    const float* __restrict__ B1, ushort* __restrict__ sH,
    int wv, int lane, int l16, int quad, int q8)
{
    f32x4 acc1[8];
    #pragma unroll
    for (int nt = 0; nt < 8; ++nt) acc1[nt] = (f32x4){0.f, 0.f, 0.f, 0.f};
    #pragma unroll
    for (int nt = 0; nt < 8; ++nt)
        acc1[nt] = __builtin_amdgcn_mfma_f32_16x16x32_bf16(af0, F1[nt * 64 + lane], acc1[nt], 0, 0, 0);
    #pragma unroll
    for (int nt = 0; nt < 8; ++nt)
        acc1[nt] = __builtin_amdgcn_mfma_f32_16x16x32_bf16(af1, F1[(8 + nt) * 64 + lane], acc1[nt], 0, 0, 0);
    #pragma unroll
    for (int nt = 0; nt < 8; ++nt)
        acc1[nt] = __builtin_amdgcn_mfma_f32_16x16x32_bf16(af2, F1[(16 + nt) * 64 + lane], acc1[nt], 0, 0, 0);
    #pragma unroll
    for (int nt = 0; nt < 8; ++nt) {
        const int col = nt * 16 + l16;
        const float bias = B1[col];
        #pragma unroll
        for (int rg = 0; rg < 4; ++rg) {
            const int rowm = wv * 16 + quad * 4 + rg;
            float s = acc1[nt][rg] + bias;
            float e = __expf(2.0f * s);
            float hh = 1.0f - __fdividef(2.0f, e + 1.0f);
            sH[rowm * SH_STRIDE + col] = f2bf(hh);
        }
    }
    Acc2 o;
    o.a0 = (f32x4){0.f, 0.f, 0.f, 0.f};
    o.a1 = (f32x4){0.f, 0.f, 0.f, 0.f};
    #pragma unroll
    for (int ks = 0; ks < 4; ++ks) {
        short8 af = *(const short8*)&sH[(wv * 16 + l16) * SH_STRIDE + ks * 32 + q8];
        o.a0 = __builtin_amdgcn_mfma_f32_16x16x32_bf16(af, w2[ks * 2 + 0], o.a0, 0, 0, 0);
        o.a1 = __builtin_amdgcn_mfma_f32_16x16x32_bf16(af, w2[ks * 2 + 1], o.a1, 0, 0, 0);
    }
    return o;
}

// Wave-autonomous rings with SELF-VALIDATING tagged exchange (r6/r10-proven).
// Reads initial state + xi directly from x (no out pre-population);
// final write-out emits q, p AND xi (fp32 copy from x). Loop untouched.
__global__ __launch_bounds__(256, 2) void sympl_coop(
    float* __restrict__ out, const float* __restrict__ x,
    const float* __restrict__ tfinal,
    char* __restrict__ ws,
    const float* __restrict__ b1q, const float* __restrict__ b2q,
    const float* __restrict__ b1p, const float* __restrict__ b2p)
{
    __shared__ __align__(16) float  sQ[64 * SQ_STRIDE];
    __shared__ __align__(16) float  sP[64 * SQ_STRIDE];
    __shared__ __align__(16) ushort sH[64 * SH_STRIDE];
    __shared__ __align__(16) float  sO[4 * 512];
    __shared__ uint ldsF[4];

    u64* eb = (u64*)(ws + OFF_EBUF);
    const int blk = blockIdx.x, tid = threadIdx.x;
    const int b = blk >> 6, r = blk & 63;
    const int wv = tid >> 6, lane = tid & 63;
    const int l16 = lane & 15, quad = lane >> 4, q8 = quad * 8;
    const int c = wv * 16 + l16;
    const int rm = (r + 63) & 63, rp = (r + 1) & 63;
    const int cm = (c + 63) & 63, cp = (c + 1) & 63;
    const int pt = tid >> 2, sg = (tid & 3) * 8;

    // neighbor-row chunk pointers (this lane's quad region of col c)
    const u64* prm = eb + ((size_t)(b * 64 + rm) * 64 + c) * 24 + quad * 3;
    const u64* prp = eb + ((size_t)(b * 64 + rp) * 64 + c) * 24 + quad * 3;
    // sentinel = last u64 the neighbor wave stores (pt wv*16+15, qR3,u2)
    const u64* s_rm = eb + ((size_t)(b * 64 + rm) * 64 + (wv * 16 + 15)) * 24 + 11;
    const u64* s_rp = eb + ((size_t)(b * 64 + rp) * 64 + (wv * 16 + 15)) * 24 + 11;
    u64* pub = eb + ((size_t)(b * 64 + r) * 64) * 24;

    // ---- init: own-row q/p from x -> LDS fp32; xi + W2 fragments -> regs ----
    {
        const float* src = x + (size_t)(b * NPTS + r * GRID_W + pt) * DIN;
        *(float4*)&sQ[pt * SQ_STRIDE + sg]     = *(const float4*)(src + sg);
        *(float4*)&sQ[pt * SQ_STRIDE + sg + 4] = *(const float4*)(src + sg + 4);
        *(float4*)&sP[pt * SQ_STRIDE + sg]     = *(const float4*)(src + DD + sg);
        *(float4*)&sP[pt * SQ_STRIDE + sg + 4] = *(const float4*)(src + DD + sg + 4);
    }
    if (tid < 4) ldsF[tid] = 0;
    short8 af2;
    if (quad < 2) {
        const float* px = x + (size_t)(b * NPTS + r * GRID_W + c) * DIN + 2 * DD + q8;
        af2 = pack8(*(const float4*)px, *(const float4*)(px + 4));
    } else {
        af2 = (short8)(short)0;
    }
    short8 w2q[8], w2p[8];
    {
        const short8* F2q = (const short8*)(ws + OFF_F2Q);
        const short8* F2p = (const short8*)(ws + OFF_F2P);
        #pragma unroll
        for (int i = 0; i < 8; ++i) { w2q[i] = F2q[i * 64 + lane]; w2p[i] = F2p[i * 64 + lane]; }
    }
    const float tf = tfinal[b];
    __syncthreads();                        // LDS state + ldsF visible

    const int wl = (wv + 3) & 3, wr = (wv + 1) & 3;

    float tq = 0.0f, tp = 0.0f;
    #pragma unroll 1
    for (int h = 0; h < NSTEP; ++h) {
        const int phase = h & 1;            // 0: q += dt*F(p); 1: p += dt*F(q)
        const float dtmax = phase ? 0.25f : ((h == 0) ? 0.125f : 0.25f);
        const float tcur  = phase ? tp : tq;
        if (!phase && tq >= tf) break;      // batch-uniform: all rings exit together
        const float dt = fminf(fmaxf(tf - tcur, 0.0f), dtmax);
        const int srcH = phase ^ 1;         // half read (q=0,p=1)
        const int dstH = phase;             // half written
        const float* srcL = phase ? sQ : sP;
        float*       dstL = phase ? sP : sQ;
        const short8* F1 = (const short8*)(ws + (phase ? OFF_F1P : OFF_F1Q));
        const uint hh = (uint)h;

        f32x4 acc1[8];
        if (dt > 0.0f) {                    // pre-wait: self + xi MFMAs
            const float* s0p = srcL + c * SQ_STRIDE + q8;
            float4 a0 = *(const float4*)s0p, a1 = *(const float4*)(s0p + 4);
            short8 af0 = pack8(a0, a1);
            #pragma unroll
            for (int nt = 0; nt < 8; ++nt) acc1[nt] = (f32x4){0.f, 0.f, 0.f, 0.f};
            #pragma unroll
            for (int nt = 0; nt < 8; ++nt)
                acc1[nt] = __builtin_amdgcn_mfma_f32_16x16x32_bf16(af0, F1[nt * 64 + lane], acc1[nt], 0, 0, 0);
            #pragma unroll
            for (int nt = 0; nt < 8; ++nt)
                acc1[nt] = __builtin_amdgcn_mfma_f32_16x16x32_bf16(af2, F1[(16 + nt) * 64 + lane], acc1[nt], 0, 0, 0);
        }

        // ---- wait: row sentinels (tagged data) + column LDS flags ----
        {
            int spins = 0;
            while (true) {
                bool ok = true;
                if (lane == 0)      ok = ((uint)(ld_sys64(s_rm + srcH * 12) >> 48) == hh);
                else if (lane == 1) ok = ((uint)(ld_sys64(s_rp + srcH * 12) >> 48) == hh);
                else if (lane == 2) ok = (__hip_atomic_load(&ldsF[wl], __ATOMIC_RELAXED, __HIP_MEMORY_SCOPE_WORKGROUP) >= hh);
                else if (lane == 3) ok = (__hip_atomic_load(&ldsF[wr], __ATOMIC_RELAXED, __HIP_MEMORY_SCOPE_WORKGROUP) >= hh);
                if (__all((int)ok)) break;
                if (++spins > SPIN_CAP) break;      // terminate, never hang
                __builtin_amdgcn_s_sleep(1);
            }
        }

        if (dt > 0.0f) {                    // block-uniform
            // validated neighbor loads: 6 self-validating u64 per lane
            const u64* pA = prm + srcH * 12;
            const u64* pB = prp + srcH * 12;
            u64 a0, a1, a2, c0, c1, c2;
            int spins = 0;
            while (true) {
                a0 = ld_sys64(pA);     a1 = ld_sys64(pA + 1); a2 = ld_sys64(pA + 2);
                c0 = ld_sys64(pB);     c1 = ld_sys64(pB + 1); c2 = ld_sys64(pB + 2);
                bool ok = ((uint)(a0 >> 48) == hh) & ((uint)(a1 >> 48) == hh)
                        & ((uint)(a2 >> 48) == hh) & ((uint)(c0 >> 48) == hh)
                        & ((uint)(c1 >> 48) == hh) & ((uint)(c2 >> 48) == hh);
                if (__all((int)ok)) break;
                if (++spins > SPIN_CAP) break;      // terminate, never hang
                __builtin_amdgcn_s_sleep(1);
            }

            // column neighbors (LDS) + row neighbors (loads) -> af1
            const float* smp = srcL + cm * SQ_STRIDE + q8;
            const float* spp = srcL + cp * SQ_STRIDE + q8;
            float4 lf0 = *(const float4*)smp, lf1 = *(const float4*)(smp + 4);
            float4 rt0 = *(const float4*)spp, rt1 = *(const float4*)(spp + 4);
            float4 m0, m1;
            m0.x = 0.25f * (bf2f((ushort)a0)         + bf2f((ushort)c0)         + lf0.x + rt0.x);
            m0.y = 0.25f * (bf2f((ushort)(a0 >> 16)) + bf2f((ushort)(c0 >> 16)) + lf0.y + rt0.y);
            m0.z = 0.25f * (bf2f((ushort)(a0 >> 32)) + bf2f((ushort)(c0 >> 32)) + lf0.z + rt0.z);
            m0.w = 0.25f * (bf2f((ushort)a1)         + bf2f((ushort)c1)         + lf0.w + rt0.w);
            m1.x = 0.25f * (bf2f((ushort)(a1 >> 16)) + bf2f((ushort)(c1 >> 16)) + lf1.x + rt1.x);
            m1.y = 0.25f * (bf2f((ushort)(a1 >> 32)) + bf2f((ushort)(c1 >> 32)) + lf1.y + rt1.y);
            m1.z = 0.25f * (bf2f((ushort)a2)         + bf2f((ushort)c2)         + lf1.z + rt1.z);
            m1.w = 0.25f * (bf2f((ushort)(a2 >> 16)) + bf2f((ushort)(c2 >> 16)) + lf1.w + rt1.w);
            short8 af1 = pack8(m0, m1);
            #pragma unroll
            for (int nt = 0; nt < 8; ++nt)
                acc1[nt] = __builtin_amdgcn_mfma_f32_16x16x32_bf16(af1, F1[(8 + nt) * 64 + lane], acc1[nt], 0, 0, 0);

            // tanh -> sH (wave-local rows)
            const float* B1 = phase ? b1p : b1q;
            #pragma unroll
            for (int nt = 0; nt < 8; ++nt) {
                const int col = nt * 16 + l16;
                const float bias = B1[col];
                #pragma unroll
                for (int rg = 0; rg < 4; ++rg) {
                    const int rowm = wv * 16 + quad * 4 + rg;
                    float s = acc1[nt][rg] + bias;
                    float e = __expf(2.0f * s);
                    float hhv = 1.0f - __fdividef(2.0f, e + 1.0f);
                    sH[rowm * SH_STRIDE + col] = f2bf(hhv);
                }
            }
            // GEMM2 (register-resident W2)
            const short8* w2 = phase ? w2p : w2q;
            f32x4 o0 = (f32x4){0.f, 0.f, 0.f, 0.f};
            f32x4 o1 = (f32x4){0.f, 0.f, 0.f, 0.f};
            #pragma unroll
            for (int ks = 0; ks < 4; ++ks) {
                short8 af = *(const short8*)&sH[(wv * 16 + l16) * SH_STRIDE + ks * 32 + q8];
                o0 = __builtin_amdgcn_mfma_f32_16x16x32_bf16(af, w2[ks * 2 + 0], o0, 0, 0, 0);
                o1 = __builtin_amdgcn_mfma_f32_16x16x32_bf16(af, w2[ks * 2 + 1], o1, 0, 0, 0);
            }
            // O -> wave-private sO
            float* sOw = sO + wv * 512;
            const float* B2 = phase ? b2p : b2q;
            #pragma unroll
            for (int nt = 0; nt < 2; ++nt) {
                const int col = nt * 16 + l16;
                const float b2v = B2[col];
                const f32x4 av = nt ? o1 : o0;
                #pragma unroll
                for (int rg = 0; rg < 4; ++rg)
                    sOw[(quad * 4 + rg) * DD + col] = av[rg] + b2v;
            }
            // LDS fp32 RMW (wave-private rows; LDS only — no global stores here)
            #pragma unroll
            for (int it = 0; it < 2; ++it) {
                const int slot = lane + it * 64;   // 128 float4 slots = 16 rows x 8
                const int lr = slot >> 3, seg = (slot & 7) * 4;
                const int pt_ = wv * 16 + lr;
                const float* po = &sOw[lr * DD + seg];
                float* pl = dstL + pt_ * SQ_STRIDE + seg;
                float4 o = *(const float4*)pl;
                o.x += dt * po[0]; o.y += dt * po[1];
                o.z += dt * po[2]; o.w += dt * po[3];
                *(float4*)pl = o;
            }
            // publish: 3 tagged u64 per lane (tag h+1), fire-and-forget
            const u64 tg = ((u64)(ushort)(hh + 1)) << 48;
            #pragma unroll
            for (int t = 0; t < 3; ++t) {
                const int g = t * 64 + lane;            // 0..191
                const int pt_ = g / 12, sub = g - pt_ * 12;
                const int qR = sub / 3, u = sub - qR * 3;
                const int sbase = qR * 8 + u * 3, cap = qR * 8 + 7;
                const int i1 = (sbase + 1 > cap) ? cap : sbase + 1;
                const int i2 = (sbase + 2 > cap) ? cap : sbase + 2;
                const float* pd = dstL + (wv * 16 + pt_) * SQ_STRIDE;
                u64 pk = (u64)f2bf(pd[sbase]) | ((u64)f2bf(pd[i1]) << 16)
                       | ((u64)f2bf(pd[i2]) << 32) | tg;
                st_sys64(pub + (size_t)(wv * 16 + pt_) * 24 + dstH * 12 + qR * 3 + u, pk);
            }
        }
        // column handshake: LDS writes drained, then per-wave flag
        __asm__ volatile("s_waitcnt lgkmcnt(0)" ::: "memory");
        if (lane == 0)
            __hip_atomic_store(&ldsF[wv], (uint)(h + 1), __ATOMIC_RELAXED, __HIP_MEMORY_SCOPE_WORKGROUP);
        if (phase) tp += dtmax; else tq += dtmax;
    }

    // ---- final state -> d_out: q, p from LDS; xi copied fp32 from x ----
    {
        float* dst = out + (size_t)(b * NPTS + r * GRID_W + pt) * DIN;
        const float* sx = x + (size_t)(b * NPTS + r * GRID_W + pt) * DIN;
        *(float4*)(dst + sg)          = *(const float4*)&sQ[pt * SQ_STRIDE + sg];
        *(float4*)(dst + sg + 4)      = *(const float4*)&sQ[pt * SQ_STRIDE + sg + 4];
        *(float4*)(dst + DD + sg)     = *(const float4*)&sP[pt * SQ_STRIDE + sg];
        *(float4*)(dst + DD + sg + 4) = *(const float4*)&sP[pt * SQ_STRIDE + sg + 4];
        const int xo = 2 * DD + (tid & 3) * 4;   // 16 xi floats / 4 threads
        *(float4*)(dst + xo) = *(const float4*)(sx + xo);
    }
}

// ---------------- fallback path (proven, global fp32 state) ----------------
__global__ __launch_bounds__(256, 2) void sympl_step(
    float* __restrict__ state, const float* __restrict__ tfinal,
    const char* __restrict__ ws,
    const float* __restrict__ B1, const float* __restrict__ B2,
    int phase, float tcur, float dtmax)
{
    __shared__ __align__(16) ushort sH[64 * SH_STRIDE];
    __shared__ __align__(16) float  sO[4 * 512];
    const int blk = blockIdx.x, tid = threadIdx.x;
    const int wv = tid >> 6, lane = tid & 63;
    const int l16 = lane & 15, quad = lane >> 4, q8 = quad * 8;
    const int b = blk >> 6, r = blk & 63;
    const int c = wv * 16 + l16;

    const float tf = tfinal[b];
    const float dt = fminf(fmaxf(tf - tcur, 0.0f), dtmax);
    if (dt <= 0.0f) return;

    const int srcoff = phase ? 0 : DD;
    const int dstoff = phase ? DD : 0;
    float* bb = state + (size_t)b * NPTS * DIN;
    const float* selfp = bb + (r * GRID_W + c) * DIN;
    const int rm = (r + 63) & 63, rp = (r + 1) & 63;
    const int cm = (c + 63) & 63, cp = (c + 1) & 63;
    short8 af0, af1, af2;
    {
        const float* ps = selfp + srcoff + q8;
        af0 = pack8(*(const float4*)ps, *(const float4*)(ps + 4));
    }
    {
        const float* p0 = bb + (rm * GRID_W + c) * DIN + srcoff + q8;
        const float* p1 = bb + (rp * GRID_W + c) * DIN + srcoff + q8;
        const float* p2 = bb + (r * GRID_W + cm) * DIN + srcoff + q8;
        const float* p3 = bb + (r * GRID_W + cp) * DIN + srcoff + q8;
        float4 a0 = *(const float4*)p0, a1 = *(const float4*)(p0 + 4);
        float4 b0 = *(const float4*)p1, b1v = *(const float4*)(p1 + 4);
        float4 c0 = *(const float4*)p2, c1 = *(const float4*)(p2 + 4);
        float4 d0 = *(const float4*)p3, d1 = *(const float4*)(p3 + 4);
        float4 m0, m1;
        m0.x = 0.25f * (a0.x + b0.x + c0.x + d0.x);
        m0.y = 0.25f * (a0.y + b0.y + c0.y + d0.y);
        m0.z = 0.25f * (a0.z + b0.z + c0.z + d0.z);
        m0.w = 0.25f * (a0.w + b0.w + c0.w + d0.w);
        m1.x = 0.25f * (a1.x + b1v.x + c1.x + d1.x);
        m1.y = 0.25f * (a1.y + b1v.y + c1.y + d1.y);
        m1.z = 0.25f * (a1.z + b1v.z + c1.z + d1.z);
        m1.w = 0.25f * (a1.w + b1v.w + c1.w + d1.w);
        af1 = pack8(m0, m1);
    }
    if (quad < 2) {
        const float* px = selfp + 2 * DD + q8;
        af2 = pack8(*(const float4*)px, *(const float4*)(px + 4));
    } else {
        af2 = (short8)(short)0;
    }
    const short8* F1 = (const short8*)(ws + (phase ? OFF_F1P : OFF_F1Q));
    const short8* F2 = (const short8*)(ws + (phase ? OFF_F2P : OFF_F2Q));
    short8 w2[8];
    #pragma unroll
    for (int i = 0; i < 8; ++i) w2[i] = F2[i * 64 + lane];
    Acc2 A = eval_F(af0, af1, af2, F1, w2, B1, sH, wv, lane, l16, quad, q8);
    float* sOw = sO + wv * 512;
    #pragma unroll
    for (int nt = 0; nt < 2; ++nt) {
        const int col = nt * 16 + l16;
        const float b2v = B2[col];
        const f32x4 av = nt ? A.a1 : A.a0;
        #pragma unroll
        for (int rg = 0; rg < 4; ++rg)
            sOw[(quad * 4 + rg) * DD + col] = av[rg] + b2v;
    }
    #pragma unroll
    for (int it = 0; it < 2; ++it) {
        const int slot = lane + it * 64;
        const int lr = slot >> 3, seg = (slot & 7) * 4;
        float* pd = bb + (r * GRID_W + wv * 16 + lr) * DIN + dstoff + seg;
        const float* po = &sOw[lr * DD + seg];
        float4 o = *(const float4*)pd;
        o.x += dt * po[0]; o.y += dt * po[1];
        o.z += dt * po[2]; o.w += dt * po[3];
        *(float4*)pd = o;
    }
}

extern "C" void kernel_launch(void* const* d_in, const int* in_sizes, int n_in,
                              void* d_out, int out_size, void* d_ws, size_t ws_size,
                              hipStream_t stream)
{
    const float* x   = (const float*)d_in[0];
    const float* tf  = (const float*)d_in[1];
    const float* W1q = (const float*)d_in[2];
    const float* b1q = (const float*)d_in[3];
    const float* W2q = (const float*)d_in[4];
    const float* b2q = (const float*)d_in[5];
    const float* W1p = (const float*)d_in[6];
    const float* b1p = (const float*)d_in[7];
    const float* W2p = (const float*)d_in[8];
    const float* b2p = (const float*)d_in[9];
    float* out = (float*)d_out;
    char* ws = (char*)d_ws;

    const int coop_ok = (ws_size >= WS_NEED) ? 1 : 0;

    // ONE setup launch: tagged-ebuf build + weight packing (no x->out copy).
    setup_all<<<dim3(NBLK + 2), dim3(256), 0, stream>>>(x, ws, W1q, W2q,
                                                        W1p, W2p, coop_ok);

    if (coop_ok) {
        sympl_coop<<<dim3(NBLK), dim3(256), 0, stream>>>(
            out, x, tf, ws, b1q, b2q, b1p, b2p);
    } else {
        // Fallback: out <- x, then 34 regular launches (kernel-boundary coherence).
        hipMemcpyAsync(out, x, (size_t)BATCH * NPTS * DIN * sizeof(float),
                       hipMemcpyDeviceToDevice, stream);
        float tq = 0.0f, tp = 0.0f;
        for (int h = 0; h < NSTEP; ++h) {
            const int phase = h & 1;
            const float dtmax = phase ? 0.25f : ((h == 0) ? 0.125f : 0.25f);
            const float tcur  = phase ? tp : tq;
            sympl_step<<<dim3(NBLK), dim3(256), 0, stream>>>(
                out, tf, ws, phase ? b1p : b1q, phase ? b2p : b2q,
                phase, tcur, dtmax);
            if (phase) tp += dtmax; else tq += dtmax;
        }
    }
}